// Round 1
// baseline (646.284 us; speedup 1.0000x reference)
//
#include <hip/hip_runtime.h>

#define NIMG 4

__device__ __forceinline__ float sigm(float x){ return 1.f/(1.f+__expf(-x)); }
__device__ __forceinline__ float silu(float x){ return x/(1.f+__expf(-x)); }
__device__ __forceinline__ float lrelu(float x){ return x>0.f ? x : 0.01f*x; }

// ---------- K1: tok[n,j,c] = silu(token_features[n,j,:]) @ W_token + b_token ----------
__global__ void k_tok(const float* __restrict__ tf, const float* __restrict__ Wt,
                      const float* __restrict__ bt, float* __restrict__ tok){
  __shared__ float s[256];
  const int row = blockIdx.x;          // n*128 + j
  const int c = threadIdx.x;           // 0..127
  const float* tr = tf + row*256;
  s[c] = silu(tr[c]); s[c+128] = silu(tr[c+128]);
  __syncthreads();
  float acc = bt[c];
  #pragma unroll 8
  for(int q=0;q<256;q++) acc = fmaf(s[q], Wt[q*128+c], acc);
  tok[row*128+c] = acc;
}

// ---------- K2: windowed sums S[n,ic,tap] = sum over valid positions of silu(x) ----------
template<int DIM, int ODIM>
__global__ void k_wsum(const float* __restrict__ x, float* __restrict__ S){
  __shared__ float sx[DIM*DIM*DIM];
  const float* xp = x + (size_t)blockIdx.x*(DIM*DIM*DIM);   // blockIdx = n*C + ic
  for(int p=threadIdx.x; p<DIM*DIM*DIM; p+=256) sx[p] = silu(xp[p]);
  __syncthreads();
  const int wave = threadIdx.x>>6, lane = threadIdx.x&63;
  for(int tap=wave; tap<27; tap+=4){
    const int kd=tap/9, kh=(tap/3)%3, kw=tap%3;
    const int base = kd*DIM*DIM + kh*DIM + kw;
    float ps = 0.f;
    for(int idx=lane; idx<ODIM*ODIM*ODIM; idx+=64){
      int od = idx/(ODIM*ODIM); int r = idx - od*(ODIM*ODIM);
      int oh = r/ODIM; int ow = r - oh*ODIM;
      ps += sx[base + od*DIM*DIM + oh*DIM + ow];
    }
    #pragma unroll
    for(int m=32;m>=1;m>>=1) ps += __shfl_xor(ps,m);
    if(lane==0) S[blockIdx.x*27 + tap] = ps;
  }
}

// ---------- K3: pocket path + token aggregation -> pf[n,c] ----------
__global__ void k_pf(const float* __restrict__ S1, const float* __restrict__ S0,
                     const float* __restrict__ Wc0, const float* __restrict__ bc0,
                     const float* __restrict__ Wc1, const float* __restrict__ bc1,
                     const float* __restrict__ Wp,  const float* __restrict__ bp,
                     const float* __restrict__ tok,
                     const float* __restrict__ Wcat, const float* __restrict__ bcat,
                     const float* __restrict__ Wgate,const float* __restrict__ bgate,
                     float* __restrict__ pf){
  __shared__ float pp[256];
  __shared__ float zz[384];
  const int n = blockIdx.x, c = threadIdx.x;   // c 0..127
  // p0 from ms_feat_1 conv (Wc0: [128][64][27]), averaged over 6^3=216 positions
  float acc = 0.f;
  { const float* w = Wc0 + c*64*27; const float* s = S1 + n*64*27;
    for(int q=0;q<64*27;q++) acc = fmaf(w[q], s[q], acc); }
  float p0 = bc0[c] + acc*(1.f/216.f);
  acc = 0.f;
  { const float* w = Wc1 + c*32*27; const float* s = S0 + n*32*27;
    for(int q=0;q<32*27;q++) acc = fmaf(w[q], s[q], acc); }
  float p1 = bc1[c] + acc*(1.f/2744.f);
  pp[c] = silu(p0); pp[128+c] = silu(p1);
  __syncthreads();
  float pk = bp[c];
  for(int q=0;q<256;q++) pk = fmaf(pp[q], Wp[q*128+c], pk);
  // token aggregation: sum over j, mean over j
  float ts = 0.f;
  for(int jj=0;jj<128;jj++) ts += tok[(n*128+jj)*128 + c];
  zz[c] = pk; zz[128+c] = ts; zz[256+c] = ts*(1.f/128.f);
  __syncthreads();
  float a1 = bcat[c], a2 = bgate[c];
  for(int q=0;q<384;q++){ float z = zz[q];
    a1 = fmaf(z, Wcat[q*128+c], a1); a2 = fmaf(z, Wgate[q*128+c], a2); }
  pf[n*128+c] = a1 * sigm(a2);
}

// ---------- K4: atoms[n,i,c] = lig_atom[n,i,:] @ W_atom + b_atom ; zero atom_e ----------
__global__ void k_atoms(const float* __restrict__ la, const float* __restrict__ Wa,
                        const float* __restrict__ ba, float* __restrict__ atoms,
                        float* __restrict__ atom_e){
  __shared__ float s[64];
  const int row = blockIdx.x;   // n*1024 + i
  const int c = threadIdx.x;    // 0..127
  if(c < 64) s[c] = la[row*64 + c];
  __syncthreads();
  float acc = ba[c];
  #pragma unroll 8
  for(int k=0;k<64;k++) acc = fmaf(s[k], Wa[k*128+c], acc);
  atoms[row*128+c] = acc;
  if(c==0) atom_e[row] = 0.f;
}

// ---------- K5: the big fused interaction GEMM ----------
// block = (n, j); per block: H = atoms[n] (1024x128) @ (diag(tok[n,j]) * W_int) (128x128)
// fused epilogue: h = lrelu(H + b_int); pe = (h.W_pe + b_pe)*sigmoid(h.W_pg + b_pg);
// atom_e[n,i] += pe   (atomic over the 128 j-blocks)
__global__ __launch_bounds__(256) void k_inter(
    const float* __restrict__ atoms, const float* __restrict__ tok,
    const float* __restrict__ Wint, const float* __restrict__ bint,
    const float* __restrict__ Wpe, const float* __restrict__ bpe,
    const float* __restrict__ Wpg, const float* __restrict__ bpg,
    float* __restrict__ atom_e){
  extern __shared__ float lds[];
  float* Bs   = lds;                     // [128][128]
  float* As   = lds + 16384;             // [128 rows][stride 132]
  float* trow = lds + 16384 + 128*132;   // [128]
  const int n = blockIdx.x >> 7, j = blockIdx.x & 127;
  const int tid = threadIdx.x;
  const int tx = tid & 15, ty = tid >> 4;   // 16 x 16
  if(tid < 128) trow[tid] = tok[(n*128+j)*128 + tid];
  __syncthreads();
  for(int q=tid; q<16384; q+=256) Bs[q] = trow[q>>7] * Wint[q];
  // epilogue constants for this thread's 8 columns: c = tx*4 + (u&3) + (u>>2)*64
  float wpe[8], wpg[8], bi[8];
  #pragma unroll
  for(int u=0;u<8;u++){
    int c = tx*4 + (u&3) + (u>>2)*64;
    wpe[u]=Wpe[c]; wpg[u]=Wpg[c]; bi[u]=bint[c];
  }
  const float bpe0 = bpe[0], bpg0 = bpg[0];
  const float* An = atoms + (size_t)n*1024*128;
  float* ae = atom_e + n*1024;

  for(int it=0; it<8; ++it){
    __syncthreads();
    // stage 128 rows of A (row-major, stride 132 to avoid bank conflicts)
    for(int q=tid; q<4096; q+=256){
      int rl = q>>5, k4 = q&31;
      *(float4*)(As + rl*132 + k4*4) =
          *(const float4*)(An + (size_t)(it*128+rl)*128 + k4*4);
    }
    __syncthreads();
    float acc[8][8];
    #pragma unroll
    for(int r=0;r<8;r++){
      #pragma unroll
      for(int u=0;u<8;u++) acc[r][u]=0.f;
    }
    for(int k4=0;k4<32;k4++){
      float4 a[8], b0[4], b1[4];
      #pragma unroll
      for(int r=0;r<8;r++) a[r] = *(const float4*)(As + (ty + 16*r)*132 + k4*4);
      #pragma unroll
      for(int kk=0;kk<4;kk++){
        b0[kk] = *(const float4*)(Bs + (k4*4+kk)*128 + tx*4);
        b1[kk] = *(const float4*)(Bs + (k4*4+kk)*128 + tx*4 + 64);
      }
      #pragma unroll
      for(int kk=0;kk<4;kk++){
        #pragma unroll
        for(int r=0;r<8;r++){
          const float av = ((const float*)(a+r))[kk];
          acc[r][0] = fmaf(av, b0[kk].x, acc[r][0]);
          acc[r][1] = fmaf(av, b0[kk].y, acc[r][1]);
          acc[r][2] = fmaf(av, b0[kk].z, acc[r][2]);
          acc[r][3] = fmaf(av, b0[kk].w, acc[r][3]);
          acc[r][4] = fmaf(av, b1[kk].x, acc[r][4]);
          acc[r][5] = fmaf(av, b1[kk].y, acc[r][5]);
          acc[r][6] = fmaf(av, b1[kk].z, acc[r][6]);
          acc[r][7] = fmaf(av, b1[kk].w, acc[r][7]);
        }
      }
    }
    // fused epilogue: rows i = it*128 + ty + 16*r
    #pragma unroll
    for(int r=0;r<8;r++){
      float d1=0.f, d2=0.f;
      #pragma unroll
      for(int u=0;u<8;u++){
        float hv = lrelu(acc[r][u] + bi[u]);
        d1 = fmaf(hv, wpe[u], d1);
        d2 = fmaf(hv, wpg[u], d2);
      }
      d1 += __shfl_xor(d1,1); d2 += __shfl_xor(d2,1);
      d1 += __shfl_xor(d1,2); d2 += __shfl_xor(d2,2);
      d1 += __shfl_xor(d1,4); d2 += __shfl_xor(d2,4);
      d1 += __shfl_xor(d1,8); d2 += __shfl_xor(d2,8);
      if(tx==0){
        float pe = (d1+bpe0) * sigm(d2+bpg0);
        atomicAdd(ae + it*128 + ty + 16*r, pe);
      }
    }
  }
}

// ---------- K6: bias head -> out[n,g] = bias (seg added later) ----------
__global__ void k_bias(const float* __restrict__ lg, const float* __restrict__ Wg,
                       const float* __restrict__ bg, const float* __restrict__ pf,
                       const float* __restrict__ W1, const float* __restrict__ b1,
                       const float* __restrict__ W2, const float* __restrict__ b2,
                       float* __restrict__ out){
  __shared__ float row[64];
  __shared__ float z[256];
  __shared__ float red[128];
  const int b = blockIdx.x;       // n*64 + g
  const int n = b >> 6;
  const int c = threadIdx.x;      // 0..127
  if(c < 64) row[c] = lg[b*64 + c];
  __syncthreads();
  float gf = bg[c];
  #pragma unroll 8
  for(int k=0;k<64;k++) gf = fmaf(row[k], Wg[k*128+c], gf);
  z[c] = pf[n*128+c]; z[128+c] = gf;
  __syncthreads();
  float t = b1[c];
  for(int q=0;q<256;q++) t = fmaf(z[q], W1[q*128+c], t);
  t = lrelu(t);
  red[c] = t * W2[c];
  __syncthreads();
  for(int s=64;s>0;s>>=1){ if(c<s) red[c]+=red[c+s]; __syncthreads(); }
  if(c==0) out[b] = red[0] + b2[0];
}

// ---------- K7: segment sum of atom_e into out ----------
__global__ void k_seg(const float* __restrict__ atom_e, const int* __restrict__ batch,
                      float* __restrict__ out){
  const int t = blockIdx.x*256 + threadIdx.x;   // 0..4095 = n*1024+i
  const int n = t >> 10, i = t & 1023;
  atomicAdd(out + n*64 + batch[i], atom_e[t]);
}

extern "C" void kernel_launch(void* const* d_in, const int* in_sizes, int n_in,
                              void* d_out, int out_size, void* d_ws, size_t ws_size,
                              hipStream_t stream) {
  const float* ms0   = (const float*)d_in[0];   // (4,32,16,16,16)
  const float* ms1   = (const float*)d_in[1];   // (4,64,8,8,8)
  const float* tfeat = (const float*)d_in[2];   // (4,128,256)
  const float* la    = (const float*)d_in[3];   // (4,1024,64)
  const float* lg    = (const float*)d_in[4];   // (4,64,64)
  const int*   batch = (const int*)  d_in[5];   // (1024,)
  const float* Wtok  = (const float*)d_in[6];
  const float* btok  = (const float*)d_in[7];
  const float* Wc0   = (const float*)d_in[8];
  const float* bc0   = (const float*)d_in[9];
  const float* Wc1   = (const float*)d_in[10];
  const float* bc1   = (const float*)d_in[11];
  const float* Wp    = (const float*)d_in[12];
  const float* bp    = (const float*)d_in[13];
  const float* Wcat  = (const float*)d_in[14];
  const float* bcat  = (const float*)d_in[15];
  const float* Wgate = (const float*)d_in[16];
  const float* bgate = (const float*)d_in[17];
  const float* Wa    = (const float*)d_in[18];
  const float* ba    = (const float*)d_in[19];
  const float* Wgr   = (const float*)d_in[20];
  const float* bgr   = (const float*)d_in[21];
  const float* W1    = (const float*)d_in[22];
  const float* b1    = (const float*)d_in[23];
  const float* W2    = (const float*)d_in[24];
  const float* b2    = (const float*)d_in[25];
  const float* Wint  = (const float*)d_in[26];
  const float* bint  = (const float*)d_in[27];
  const float* Wpe   = (const float*)d_in[28];
  const float* bpe   = (const float*)d_in[29];
  const float* Wpg   = (const float*)d_in[30];
  const float* bpg   = (const float*)d_in[31];
  float* out = (float*)d_out;

  float* ws     = (float*)d_ws;
  float* tok    = ws;                    // 4*128*128   = 65536
  float* atoms  = ws + 65536;            // 4*1024*128  = 524288
  float* S1     = ws + 65536 + 524288;   // 4*64*27     = 6912
  float* S0     = S1 + 6912;             // 4*32*27     = 3456
  float* pf     = S0 + 3456;             // 4*128       = 512
  float* atom_e = pf + 512;              // 4*1024      = 4096

  k_tok<<<NIMG*128, 128, 0, stream>>>(tfeat, Wtok, btok, tok);
  k_wsum<8,6><<<NIMG*64, 256, 0, stream>>>(ms1, S1);
  k_wsum<16,14><<<NIMG*32, 256, 0, stream>>>(ms0, S0);
  k_pf<<<NIMG, 128, 0, stream>>>(S1, S0, Wc0, bc0, Wc1, bc1, Wp, bp,
                                 tok, Wcat, bcat, Wgate, bgate, pf);
  k_atoms<<<NIMG*1024, 128, 0, stream>>>(la, Wa, ba, atoms, atom_e);

  const int lds_bytes = (16384 + 128*132 + 128) * 4;   // 133632
  hipFuncSetAttribute(reinterpret_cast<const void*>(k_inter),
                      hipFuncAttributeMaxDynamicSharedMemorySize, lds_bytes);
  k_inter<<<NIMG*128, 256, lds_bytes, stream>>>(atoms, tok, Wint, bint,
                                                Wpe, bpe, Wpg, bpg, atom_e);

  k_bias<<<NIMG*64, 128, 0, stream>>>(lg, Wgr, bgr, pf, W1, b1, W2, b2, out);
  k_seg<<<16, 256, 0, stream>>>(atom_e, batch, out);
}

// Round 2
// 319.283 us; speedup vs baseline: 2.0242x; 2.0242x over previous
//
#include <hip/hip_runtime.h>
#include <hip/hip_bf16.h>

#define NIMG 4

typedef __attribute__((ext_vector_type(8))) short short8v;
typedef __attribute__((ext_vector_type(4))) float float4v;

__device__ __forceinline__ float sigm(float x){ return 1.f/(1.f+__expf(-x)); }
__device__ __forceinline__ float silu(float x){ return x/(1.f+__expf(-x)); }
__device__ __forceinline__ float lrelu(float x){ return fmaxf(x, 0.01f*x); }
__device__ __forceinline__ float bf2f(unsigned short u){
  union { unsigned int i; float f; } v; v.i = ((unsigned int)u)<<16; return v.f; }
__device__ __forceinline__ unsigned short f2bf(float f){
  union { float f; unsigned int i; } v; v.f = f;
  unsigned int r = v.i + 0x7fffu + ((v.i>>16)&1u);
  return (unsigned short)(r>>16); }

// ---------- K1: tok[n,j,c] = silu(token_features[n,j,:]) @ W_token + b_token ----------
__global__ void k_tok(const float* __restrict__ tf, const float* __restrict__ Wt,
                      const float* __restrict__ bt, float* __restrict__ tok){
  __shared__ float s[256];
  const int row = blockIdx.x;          // n*128 + j
  const int c = threadIdx.x;           // 0..127
  const float* tr = tf + row*256;
  s[c] = silu(tr[c]); s[c+128] = silu(tr[c+128]);
  __syncthreads();
  float acc = bt[c];
  #pragma unroll 8
  for(int q=0;q<256;q++) acc = fmaf(s[q], Wt[q*128+c], acc);
  tok[row*128+c] = acc;
}

// ---------- K2: windowed sums over silu(x) ----------
template<int DIM, int ODIM>
__global__ void k_wsum(const float* __restrict__ x, float* __restrict__ S){
  __shared__ float sx[DIM*DIM*DIM];
  const float* xp = x + (size_t)blockIdx.x*(DIM*DIM*DIM);   // blockIdx = n*C + ic
  for(int p=threadIdx.x; p<DIM*DIM*DIM; p+=256) sx[p] = silu(xp[p]);
  __syncthreads();
  const int wave = threadIdx.x>>6, lane = threadIdx.x&63;
  for(int tap=wave; tap<27; tap+=4){
    const int kd=tap/9, kh=(tap/3)%3, kw=tap%3;
    const int base = kd*DIM*DIM + kh*DIM + kw;
    float ps = 0.f;
    for(int idx=lane; idx<ODIM*ODIM*ODIM; idx+=64){
      int od = idx/(ODIM*ODIM); int r = idx - od*(ODIM*ODIM);
      int oh = r/ODIM; int ow = r - oh*ODIM;
      ps += sx[base + od*DIM*DIM + oh*DIM + ow];
    }
    #pragma unroll
    for(int m=32;m>=1;m>>=1) ps += __shfl_xor(ps,m);
    if(lane==0) S[blockIdx.x*27 + tap] = ps;
  }
}

// ---------- K3: pocket path + token aggregation -> pf[n,c] ----------
__global__ void k_pf(const float* __restrict__ S1, const float* __restrict__ S0,
                     const float* __restrict__ Wc0, const float* __restrict__ bc0,
                     const float* __restrict__ Wc1, const float* __restrict__ bc1,
                     const float* __restrict__ Wp,  const float* __restrict__ bp,
                     const float* __restrict__ tok,
                     const float* __restrict__ Wcat, const float* __restrict__ bcat,
                     const float* __restrict__ Wgate,const float* __restrict__ bgate,
                     float* __restrict__ pf){
  __shared__ float pp[256];
  __shared__ float zz[384];
  const int n = blockIdx.x, c = threadIdx.x;   // c 0..127
  float acc = 0.f;
  { const float* w = Wc0 + c*64*27; const float* s = S1 + n*64*27;
    for(int q=0;q<64*27;q++) acc = fmaf(w[q], s[q], acc); }
  float p0 = bc0[c] + acc*(1.f/216.f);
  acc = 0.f;
  { const float* w = Wc1 + c*32*27; const float* s = S0 + n*32*27;
    for(int q=0;q<32*27;q++) acc = fmaf(w[q], s[q], acc); }
  float p1 = bc1[c] + acc*(1.f/2744.f);
  pp[c] = silu(p0); pp[128+c] = silu(p1);
  __syncthreads();
  float pk = bp[c];
  for(int q=0;q<256;q++) pk = fmaf(pp[q], Wp[q*128+c], pk);
  float ts = 0.f;
  for(int jj=0;jj<128;jj++) ts += tok[(n*128+jj)*128 + c];
  zz[c] = pk; zz[128+c] = ts; zz[256+c] = ts*(1.f/128.f);
  __syncthreads();
  float a1 = bcat[c], a2 = bgate[c];
  for(int q=0;q<384;q++){ float z = zz[q];
    a1 = fmaf(z, Wcat[q*128+c], a1); a2 = fmaf(z, Wgate[q*128+c], a2); }
  pf[n*128+c] = a1 * sigm(a2);
}

// ---------- K4: atoms (bf16) + zero atom_e ----------
__global__ void k_atoms(const float* __restrict__ la, const float* __restrict__ Wa,
                        const float* __restrict__ ba, unsigned short* __restrict__ atoms_bf,
                        float* __restrict__ atom_e){
  __shared__ float s[64];
  const int row = blockIdx.x;   // n*1024 + i
  const int c = threadIdx.x;    // 0..127
  if(c < 64) s[c] = la[row*64 + c];
  __syncthreads();
  float acc = ba[c];
  #pragma unroll 8
  for(int k=0;k<64;k++) acc = fmaf(s[k], Wa[k*128+c], acc);
  atoms_bf[row*128+c] = f2bf(acc);
  if(c==0) atom_e[row] = 0.f;
}

// ---------- K4b: Wt[c][k] = bf16(W_int[k][c]) ----------
__global__ void k_wt(const float* __restrict__ Wint, unsigned short* __restrict__ Wt){
  const int c = blockIdx.x, k = threadIdx.x;
  Wt[c*128 + k] = f2bf(Wint[k*128 + c]);
}

// ---------- K5: fused interaction via bf16 MFMA ----------
// block = (n, chunk of 256 atoms, group of 4 j). 8 waves in 4(row)x2(col) grid
// of 64x64 tiles. A-fragments in registers; scaled-B built in LDS per j
// (double-buffered, XOR-swizzled); epilogue fused; pe accumulated over j.
__global__ __launch_bounds__(512,2) void k_inter(
    const unsigned short* __restrict__ atoms_bf,  // [4*1024][128] bf16
    const float* __restrict__ tok,                // [4*128][128] f32
    const unsigned short* __restrict__ Wt,        // [128 c][128 k] bf16 (W_int^T)
    const float* __restrict__ bint,
    const float* __restrict__ Wpe, const float* __restrict__ bpe,
    const float* __restrict__ Wpg, const float* __restrict__ bpg,
    float* __restrict__ atom_e){
  extern __shared__ unsigned short ldsu[];        // [2][128*128] bf16 B + red
  float* red = (float*)(ldsu + 32768);            // [2][256][2] f32

  const int b0 = blockIdx.x;
  const int bid = (b0 & 7)*64 + (b0 >> 3);        // XCD swizzle (512%8==0)
  const int n = bid >> 7;
  const int chunk = (bid >> 5) & 3;
  const int jg = bid & 31;                        // j base = jg*4
  const int tid = threadIdx.x;
  const int wv = tid >> 6, lane = tid & 63;
  const int q = lane >> 4, t = lane & 15;
  const int wr = wv >> 1, wc = wv & 1;

  const int rbase = n*1024 + chunk*256;

  // ---- A fragments: row = wr*64 + fr*16 + t, k = ks*32 + q*8 ----
  short8v areg[4][4];
  const unsigned short* ab = atoms_bf + (size_t)rbase*128 + (wr*64 + t)*128 + q*8;
  #pragma unroll
  for(int fr=0; fr<4; fr++)
    #pragma unroll
    for(int ks=0; ks<4; ks++)
      areg[fr][ks] = *(const short8v*)(ab + fr*16*128 + ks*32);

  // ---- W_int^T resident in registers (f32): c = cbb+32i, k = kq..kq+7 ----
  const int kq = (tid & 15)*8;
  const int cbb = tid >> 4;             // 0..31
  const int swzW = (cbb & 7) << 3;
  float wf[4][8];
  {
    short8v wtmp[4];
    #pragma unroll
    for(int i=0;i<4;i++) wtmp[i] = *(const short8v*)(Wt + (cbb + 32*i)*128 + kq);
    #pragma unroll
    for(int i=0;i<4;i++)
      #pragma unroll
      for(int e=0;e<8;e++) wf[i][e] = bf2f((unsigned short)wtmp[i][e]);
  }
  const float* tokb = tok + (size_t)(n*128 + jg*4)*128;

  // epilogue constants
  float bi[4], wpe[4], wpg[4];
  #pragma unroll
  for(int fc=0; fc<4; fc++){
    int c = wc*64 + fc*16 + t;
    bi[fc] = bint[c]; wpe[fc] = Wpe[c]; wpg[fc] = Wpg[c];
  }
  const float bpe0 = bpe[0], bpg0 = bpg[0];
  const int swzB = (t & 7) << 3;

  float peacc = 0.f;

  // ---- build j=0 into buffer 0 ----
  {
    float4v t0 = *(const float4v*)(tokb + kq);
    float4v t1 = *(const float4v*)(tokb + kq + 4);
    float trv[8] = {t0[0],t0[1],t0[2],t0[3],t1[0],t1[1],t1[2],t1[3]};
    #pragma unroll
    for(int i=0;i<4;i++){
      int c = cbb + 32*i;
      short8v o;
      #pragma unroll
      for(int e=0;e<8;e++) o[e] = (short)f2bf(wf[i][e]*trv[e]);
      *(short8v*)(ldsu + (c<<7) + (kq ^ swzW)) = o;
    }
  }
  __syncthreads();

  #pragma unroll
  for(int j=0; j<4; j++){
    // issue next-j tok loads early (hidden under MFMA+epilogue)
    float trn[8];
    if(j<3){
      float4v t0 = *(const float4v*)(tokb + (j+1)*128 + kq);
      float4v t1 = *(const float4v*)(tokb + (j+1)*128 + kq + 4);
      #pragma unroll
      for(int e=0;e<4;e++){ trn[e]=t0[e]; trn[4+e]=t1[e]; }
    }
    const unsigned short* B = ldsu + (j&1)*16384;

    float4v acc[4][4];
    #pragma unroll
    for(int fr=0;fr<4;fr++)
      #pragma unroll
      for(int fc=0;fc<4;fc++)
        acc[fr][fc] = (float4v){bi[fc],bi[fc],bi[fc],bi[fc]};

    #pragma unroll
    for(int ks=0;ks<4;ks++){
      #pragma unroll
      for(int fc=0;fc<4;fc++){
        const int c = wc*64 + fc*16 + t;
        short8v bf = *(const short8v*)(B + (c<<7) + ((ks*32 + q*8) ^ swzB));
        #pragma unroll
        for(int fr=0;fr<4;fr++)
          acc[fr][fc] = __builtin_amdgcn_mfma_f32_16x16x32_bf16(areg[fr][ks], bf, acc[fr][fc], 0,0,0);
      }
    }

    // fused epilogue: h = lrelu(H + bint) (bias in C-init); partial dots
    #pragma unroll
    for(int fr=0;fr<4;fr++){
      #pragma unroll
      for(int r=0;r<4;r++){
        float d1=0.f, d2=0.f;
        #pragma unroll
        for(int fc=0;fc<4;fc++){
          float h = lrelu(acc[fr][fc][r]);
          d1 = fmaf(h, wpe[fc], d1);
          d2 = fmaf(h, wpg[fc], d2);
        }
        d1 += __shfl_xor(d1,1); d2 += __shfl_xor(d2,1);
        d1 += __shfl_xor(d1,2); d2 += __shfl_xor(d2,2);
        d1 += __shfl_xor(d1,4); d2 += __shfl_xor(d2,4);
        d1 += __shfl_xor(d1,8); d2 += __shfl_xor(d2,8);
        if(t==0){
          int row = wr*64 + fr*16 + q*4 + r;
          red[(wc*256 + row)*2 + 0] = d1;
          red[(wc*256 + row)*2 + 1] = d2;
        }
      }
    }
    __syncthreads();
    if(tid < 256){
      float d1 = red[tid*2]     + red[(256+tid)*2];
      float d2 = red[tid*2 + 1] + red[(256+tid)*2 + 1];
      peacc += (d1 + bpe0) * sigm(d2 + bpg0);
    }
    if(j<3){
      #pragma unroll
      for(int i=0;i<4;i++){
        int c = cbb + 32*i;
        short8v o;
        #pragma unroll
        for(int e=0;e<8;e++) o[e] = (short)f2bf(wf[i][e]*trn[e]);
        *(short8v*)(ldsu + ((j+1)&1)*16384 + (c<<7) + (kq ^ swzW)) = o;
      }
    }
    __syncthreads();
  }
  if(tid < 256) atomicAdd(atom_e + rbase + tid, peacc);
}

// ---------- K6: bias head + fused segment-sum ----------
__global__ void k_bias_seg(const float* __restrict__ lg, const float* __restrict__ Wg,
                       const float* __restrict__ bg, const float* __restrict__ pf,
                       const float* __restrict__ W1, const float* __restrict__ b1,
                       const float* __restrict__ W2, const float* __restrict__ b2,
                       const float* __restrict__ atom_e, const int* __restrict__ batch,
                       float* __restrict__ out){
  __shared__ float row[64];
  __shared__ float z[256];
  __shared__ float red[128];
  __shared__ float red2[128];
  const int b = blockIdx.x;       // n*64 + g
  const int n = b >> 6, g = b & 63;
  const int c = threadIdx.x;      // 0..127
  if(c < 64) row[c] = lg[b*64 + c];
  __syncthreads();
  float gf = bg[c];
  #pragma unroll 8
  for(int k=0;k<64;k++) gf = fmaf(row[k], Wg[k*128+c], gf);
  z[c] = pf[n*128+c]; z[128+c] = gf;
  __syncthreads();
  float tacc = b1[c];
  for(int qq=0;qq<256;qq++) tacc = fmaf(z[qq], W1[qq*128+c], tacc);
  tacc = lrelu(tacc);
  float s = 0.f;
  const float* ae = atom_e + n*1024;
  for(int i=c;i<1024;i+=128){ float v = ae[i]; s += (batch[i]==g) ? v : 0.f; }
  red[c] = tacc * W2[c];
  red2[c] = s;
  __syncthreads();
  for(int st=64; st>0; st>>=1){
    if(c<st){ red[c]+=red[c+st]; red2[c]+=red2[c+st]; }
    __syncthreads();
  }
  if(c==0) out[b] = red[0] + b2[0] + red2[0];
}

extern "C" void kernel_launch(void* const* d_in, const int* in_sizes, int n_in,
                              void* d_out, int out_size, void* d_ws, size_t ws_size,
                              hipStream_t stream) {
  const float* ms0   = (const float*)d_in[0];
  const float* ms1   = (const float*)d_in[1];
  const float* tfeat = (const float*)d_in[2];
  const float* la    = (const float*)d_in[3];
  const float* lg    = (const float*)d_in[4];
  const int*   batch = (const int*)  d_in[5];
  const float* Wtok  = (const float*)d_in[6];
  const float* btok  = (const float*)d_in[7];
  const float* Wc0   = (const float*)d_in[8];
  const float* bc0   = (const float*)d_in[9];
  const float* Wc1   = (const float*)d_in[10];
  const float* bc1   = (const float*)d_in[11];
  const float* Wp    = (const float*)d_in[12];
  const float* bp    = (const float*)d_in[13];
  const float* Wcat  = (const float*)d_in[14];
  const float* bcat  = (const float*)d_in[15];
  const float* Wgate = (const float*)d_in[16];
  const float* bgate = (const float*)d_in[17];
  const float* Wa    = (const float*)d_in[18];
  const float* ba    = (const float*)d_in[19];
  const float* Wgr   = (const float*)d_in[20];
  const float* bgr   = (const float*)d_in[21];
  const float* W1    = (const float*)d_in[22];
  const float* b1    = (const float*)d_in[23];
  const float* W2    = (const float*)d_in[24];
  const float* b2    = (const float*)d_in[25];
  const float* Wint  = (const float*)d_in[26];
  const float* bint  = (const float*)d_in[27];
  const float* Wpe   = (const float*)d_in[28];
  const float* bpe   = (const float*)d_in[29];
  const float* Wpg   = (const float*)d_in[30];
  const float* bpg   = (const float*)d_in[31];
  float* out = (float*)d_out;

  float* ws      = (float*)d_ws;
  float* tok     = ws;                         // 65536 f32
  float* S1      = ws + 65536;                 // 6912
  float* S0      = S1 + 6912;                  // 3456
  float* pf      = S0 + 3456;                  // 512
  float* atom_e  = pf + 512;                   // 4096
  unsigned short* atoms_bf = (unsigned short*)(atom_e + 4096);   // 524288 u16
  unsigned short* Wt       = atoms_bf + 524288;                  // 16384 u16

  k_tok<<<NIMG*128, 128, 0, stream>>>(tfeat, Wtok, btok, tok);
  k_wsum<8,6><<<NIMG*64, 256, 0, stream>>>(ms1, S1);
  k_wsum<16,14><<<NIMG*32, 256, 0, stream>>>(ms0, S0);
  k_atoms<<<NIMG*1024, 128, 0, stream>>>(la, Wa, ba, atoms_bf, atom_e);
  k_wt<<<128, 128, 0, stream>>>(Wint, Wt);
  k_pf<<<NIMG, 128, 0, stream>>>(S1, S0, Wc0, bc0, Wc1, bc1, Wp, bp,
                                 tok, Wcat, bcat, Wgate, bgate, pf);

  const int lds_bytes = 65536 + 4096;   // B dbuf + red
  hipFuncSetAttribute(reinterpret_cast<const void*>(k_inter),
                      hipFuncAttributeMaxDynamicSharedMemorySize, lds_bytes);
  k_inter<<<512, 512, lds_bytes, stream>>>(atoms_bf, tok, Wt, bint,
                                           Wpe, bpe, Wpg, bpg, atom_e);

  k_bias_seg<<<NIMG*64, 128, 0, stream>>>(lg, Wgr, bgr, pf, W1, b1, W2, b2,
                                          atom_e, batch, out);
}

// Round 3
// 250.150 us; speedup vs baseline: 2.5836x; 1.2764x over previous
//
#include <hip/hip_runtime.h>
#include <hip/hip_bf16.h>

#define NIMG 4

typedef __attribute__((ext_vector_type(8))) short short8v;
typedef __attribute__((ext_vector_type(4))) float float4v;

__device__ __forceinline__ float sigm(float x){ return 1.f/(1.f+__expf(-x)); }
__device__ __forceinline__ float silu(float x){ return x/(1.f+__expf(-x)); }
__device__ __forceinline__ float lrelu(float x){ return fmaxf(x, 0.01f*x); }
__device__ __forceinline__ float bf2f(unsigned short u){
  union { unsigned int i; float f; } v; v.i = ((unsigned int)u)<<16; return v.f; }
__device__ __forceinline__ unsigned short f2bf(float f){
  union { float f; unsigned int i; } v; v.f = f;
  unsigned int r = v.i + 0x7fffu + ((v.i>>16)&1u);
  return (unsigned short)(r>>16); }

// ---------- K1: tok[n,j,c] = silu(tf[n,j,:]) @ W_token + b_token ; toksum += ----------
__global__ void k_tok(const float* __restrict__ tf, const float* __restrict__ Wt,
                      const float* __restrict__ bt, float* __restrict__ tok,
                      float* __restrict__ toksum){
  __shared__ float sv[256];
  __shared__ float part[128];
  const int row = blockIdx.x;          // n*128 + j
  const int tid = threadIdx.x;         // 0..255
  const int c = tid & 127, s = tid >> 7;
  sv[tid] = silu(tf[row*256 + tid]);
  __syncthreads();
  float acc = 0.f;
  #pragma unroll 8
  for(int q=s*128; q<s*128+128; q++) acc = fmaf(sv[q], Wt[q*128+c], acc);
  if(s==1) part[c] = acc;
  __syncthreads();
  if(s==0){
    acc += part[c] + bt[c];
    tok[row*128+c] = acc;
    atomicAdd(&toksum[(row>>7)*128 + c], acc);
  }
}

// ---------- K2: windowed sums over silu(x) ----------
template<int DIM, int ODIM>
__global__ void k_wsum(const float* __restrict__ x, float* __restrict__ S){
  __shared__ float sx[DIM*DIM*DIM];
  const float* xp = x + (size_t)blockIdx.x*(DIM*DIM*DIM);   // blockIdx = n*C + ic
  for(int p=threadIdx.x; p<DIM*DIM*DIM; p+=256) sx[p] = silu(xp[p]);
  __syncthreads();
  const int wave = threadIdx.x>>6, lane = threadIdx.x&63;
  for(int tap=wave; tap<27; tap+=4){
    const int kd=tap/9, kh=(tap/3)%3, kw=tap%3;
    const int base = kd*DIM*DIM + kh*DIM + kw;
    float ps = 0.f;
    for(int idx=lane; idx<ODIM*ODIM*ODIM; idx+=64){
      int od = idx/(ODIM*ODIM); int r = idx - od*(ODIM*ODIM);
      int oh = r/ODIM; int ow = r - oh*ODIM;
      ps += sx[base + od*DIM*DIM + oh*DIM + ow];
    }
    #pragma unroll
    for(int m=32;m>=1;m>>=1) ps += __shfl_xor(ps,m);
    if(lane==0) S[blockIdx.x*27 + tap] = ps;
  }
}

// ---------- K3a: per-(n,c) conv dot -> pp[n][0:128]=silu(p0), [128:256]=silu(p1) ----------
__global__ void k_pconv(const float* __restrict__ S1, const float* __restrict__ S0,
                        const float* __restrict__ Wc0, const float* __restrict__ bc0,
                        const float* __restrict__ Wc1, const float* __restrict__ bc1,
                        float* __restrict__ pp){
  const int b = blockIdx.x;        // n*128 + c
  const int n = b >> 7, c = b & 127;
  const int tid = threadIdx.x;     // 0..255
  float a0 = 0.f, a1 = 0.f;
  { const float* w = Wc0 + c*1728; const float* s = S1 + n*1728;
    for(int q=tid; q<1728; q+=256) a0 = fmaf(w[q], s[q], a0); }
  { const float* w = Wc1 + c*864;  const float* s = S0 + n*864;
    for(int q=tid; q<864; q+=256)  a1 = fmaf(w[q], s[q], a1); }
  #pragma unroll
  for(int m=32;m>=1;m>>=1){ a0 += __shfl_xor(a0,m); a1 += __shfl_xor(a1,m); }
  __shared__ float r0[4], r1[4];
  if((tid&63)==0){ r0[tid>>6]=a0; r1[tid>>6]=a1; }
  __syncthreads();
  if(tid==0){
    float p0 = bc0[c] + (r0[0]+r0[1]+r0[2]+r0[3])*(1.f/216.f);
    float p1 = bc1[c] + (r1[0]+r1[1]+r1[2]+r1[3])*(1.f/2744.f);
    pp[n*256 + c]       = silu(p0);
    pp[n*256 + 128 + c] = silu(p1);
  }
}

// ---------- K3b: pocket + cat/gate -> pf[n,c] ----------
__global__ void k_pf2(const float* __restrict__ pp, const float* __restrict__ toksum,
                      const float* __restrict__ Wp,  const float* __restrict__ bp,
                      const float* __restrict__ Wcat, const float* __restrict__ bcat,
                      const float* __restrict__ Wgate,const float* __restrict__ bgate,
                      float* __restrict__ pf){
  __shared__ float ps[256];
  __shared__ float zz[384];
  __shared__ float part[4][128];
  __shared__ float partg[4][128];
  const int n = blockIdx.x;
  const int tid = threadIdx.x;     // 0..511
  const int c = tid & 127, s = tid >> 7;
  if(tid < 256) ps[tid] = pp[n*256 + tid];
  __syncthreads();
  float a = 0.f;
  for(int q=s*64; q<s*64+64; q++) a = fmaf(ps[q], Wp[q*128+c], a);
  part[s][c] = a;
  __syncthreads();
  if(s==0){
    float pk = bp[c] + part[0][c]+part[1][c]+part[2][c]+part[3][c];
    float ts = toksum[n*128+c];
    zz[c] = pk; zz[128+c] = ts; zz[256+c] = ts*(1.f/128.f);
  }
  __syncthreads();
  float a1=0.f, a2=0.f;
  for(int q=s*96; q<s*96+96; q++){
    float z = zz[q];
    a1 = fmaf(z, Wcat[q*128+c], a1);
    a2 = fmaf(z, Wgate[q*128+c], a2);
  }
  part[s][c]=a1; partg[s][c]=a2;
  __syncthreads();
  if(s==0){
    float v1 = bcat[c] +part[0][c]+part[1][c]+part[2][c]+part[3][c];
    float v2 = bgate[c]+partg[0][c]+partg[1][c]+partg[2][c]+partg[3][c];
    pf[n*128+c] = v1 * sigm(v2);
  }
}

// ---------- K4: atoms (bf16) + zero atom_e ----------
__global__ void k_atoms(const float* __restrict__ la, const float* __restrict__ Wa,
                        const float* __restrict__ ba, unsigned short* __restrict__ atoms_bf,
                        float* __restrict__ atom_e){
  __shared__ float s[64];
  const int row = blockIdx.x;   // n*1024 + i
  const int c = threadIdx.x;    // 0..127
  if(c < 64) s[c] = la[row*64 + c];
  __syncthreads();
  float acc = ba[c];
  #pragma unroll 8
  for(int k=0;k<64;k++) acc = fmaf(s[k], Wa[k*128+c], acc);
  atoms_bf[row*128+c] = f2bf(acc);
  if(c==0) atom_e[row] = 0.f;
}

// ---------- K4b: Wt[c][k] = bf16(W_int[k][c]) ----------
__global__ void k_wt(const float* __restrict__ Wint, unsigned short* __restrict__ Wt){
  const int c = blockIdx.x, k = threadIdx.x;
  Wt[c*128 + k] = f2bf(Wint[k*128 + c]);
}

// ---------- K5: fused interaction via bf16 MFMA ----------
__global__ __launch_bounds__(512,2) void k_inter(
    const unsigned short* __restrict__ atoms_bf,  // [4*1024][128] bf16
    const float* __restrict__ tok,                // [4*128][128] f32
    const unsigned short* __restrict__ Wt,        // [128 c][128 k] bf16 (W_int^T)
    const float* __restrict__ bint,
    const float* __restrict__ Wpe, const float* __restrict__ bpe,
    const float* __restrict__ Wpg, const float* __restrict__ bpg,
    float* __restrict__ atom_e){
  extern __shared__ unsigned short ldsu[];        // [2][128*128] bf16 B + red
  float* red = (float*)(ldsu + 32768);            // [2][256][2] f32

  const int b0 = blockIdx.x;
  const int bid = (b0 & 7)*64 + (b0 >> 3);        // XCD swizzle (512%8==0)
  const int n = bid >> 7;
  const int chunk = (bid >> 5) & 3;
  const int jg = bid & 31;                        // j base = jg*4
  const int tid = threadIdx.x;
  const int wv = tid >> 6, lane = tid & 63;
  const int q = lane >> 4, t = lane & 15;
  const int wr = wv >> 1, wc = wv & 1;

  const int rbase = n*1024 + chunk*256;

  short8v areg[4][4];
  const unsigned short* ab = atoms_bf + (size_t)rbase*128 + (wr*64 + t)*128 + q*8;
  #pragma unroll
  for(int fr=0; fr<4; fr++)
    #pragma unroll
    for(int ks=0; ks<4; ks++)
      areg[fr][ks] = *(const short8v*)(ab + fr*16*128 + ks*32);

  const int kq = (tid & 15)*8;
  const int cbb = tid >> 4;             // 0..31
  const int swzW = (cbb & 7) << 3;
  float wf[4][8];
  {
    short8v wtmp[4];
    #pragma unroll
    for(int i=0;i<4;i++) wtmp[i] = *(const short8v*)(Wt + (cbb + 32*i)*128 + kq);
    #pragma unroll
    for(int i=0;i<4;i++)
      #pragma unroll
      for(int e=0;e<8;e++) wf[i][e] = bf2f((unsigned short)wtmp[i][e]);
  }
  const float* tokb = tok + (size_t)(n*128 + jg*4)*128;

  float bi[4], wpe[4], wpg[4];
  #pragma unroll
  for(int fc=0; fc<4; fc++){
    int c = wc*64 + fc*16 + t;
    bi[fc] = bint[c]; wpe[fc] = Wpe[c]; wpg[fc] = Wpg[c];
  }
  const float bpe0 = bpe[0], bpg0 = bpg[0];
  const int swzB = (t & 7) << 3;

  float peacc = 0.f;

  {
    float4v t0 = *(const float4v*)(tokb + kq);
    float4v t1 = *(const float4v*)(tokb + kq + 4);
    float trv[8] = {t0[0],t0[1],t0[2],t0[3],t1[0],t1[1],t1[2],t1[3]};
    #pragma unroll
    for(int i=0;i<4;i++){
      int c = cbb + 32*i;
      short8v o;
      #pragma unroll
      for(int e=0;e<8;e++) o[e] = (short)f2bf(wf[i][e]*trv[e]);
      *(short8v*)(ldsu + (c<<7) + (kq ^ swzW)) = o;
    }
  }
  __syncthreads();

  #pragma unroll
  for(int j=0; j<4; j++){
    float trn[8];
    if(j<3){
      float4v t0 = *(const float4v*)(tokb + (j+1)*128 + kq);
      float4v t1 = *(const float4v*)(tokb + (j+1)*128 + kq + 4);
      #pragma unroll
      for(int e=0;e<4;e++){ trn[e]=t0[e]; trn[4+e]=t1[e]; }
    }
    const unsigned short* B = ldsu + (j&1)*16384;

    float4v acc[4][4];
    #pragma unroll
    for(int fr=0;fr<4;fr++)
      #pragma unroll
      for(int fc=0;fc<4;fc++)
        acc[fr][fc] = (float4v){bi[fc],bi[fc],bi[fc],bi[fc]};

    #pragma unroll
    for(int ks=0;ks<4;ks++){
      #pragma unroll
      for(int fc=0;fc<4;fc++){
        const int c = wc*64 + fc*16 + t;
        short8v bf = *(const short8v*)(B + (c<<7) + ((ks*32 + q*8) ^ swzB));
        #pragma unroll
        for(int fr=0;fr<4;fr++)
          acc[fr][fc] = __builtin_amdgcn_mfma_f32_16x16x32_bf16(areg[fr][ks], bf, acc[fr][fc], 0,0,0);
      }
    }

    #pragma unroll
    for(int fr=0;fr<4;fr++){
      #pragma unroll
      for(int r=0;r<4;r++){
        float d1=0.f, d2=0.f;
        #pragma unroll
        for(int fc=0;fc<4;fc++){
          float h = lrelu(acc[fr][fc][r]);
          d1 = fmaf(h, wpe[fc], d1);
          d2 = fmaf(h, wpg[fc], d2);
        }
        d1 += __shfl_xor(d1,1); d2 += __shfl_xor(d2,1);
        d1 += __shfl_xor(d1,2); d2 += __shfl_xor(d2,2);
        d1 += __shfl_xor(d1,4); d2 += __shfl_xor(d2,4);
        d1 += __shfl_xor(d1,8); d2 += __shfl_xor(d2,8);
        if(t==0){
          int row = wr*64 + fr*16 + q*4 + r;
          red[(wc*256 + row)*2 + 0] = d1;
          red[(wc*256 + row)*2 + 1] = d2;
        }
      }
    }
    __syncthreads();
    if(tid < 256){
      float d1 = red[tid*2]     + red[(256+tid)*2];
      float d2 = red[tid*2 + 1] + red[(256+tid)*2 + 1];
      peacc += (d1 + bpe0) * sigm(d2 + bpg0);
    }
    if(j<3){
      #pragma unroll
      for(int i=0;i<4;i++){
        int c = cbb + 32*i;
        short8v o;
        #pragma unroll
        for(int e=0;e<8;e++) o[e] = (short)f2bf(wf[i][e]*trn[e]);
        *(short8v*)(ldsu + ((j+1)&1)*16384 + (c<<7) + (kq ^ swzW)) = o;
      }
    }
    __syncthreads();
  }
  if(tid < 256) atomicAdd(atom_e + rbase + tid, peacc);
}

// ---------- K6: bias head + fused segment-sum ----------
__global__ void k_bias_seg(const float* __restrict__ lg, const float* __restrict__ Wg,
                       const float* __restrict__ bg, const float* __restrict__ pf,
                       const float* __restrict__ W1, const float* __restrict__ b1,
                       const float* __restrict__ W2, const float* __restrict__ b2,
                       const float* __restrict__ atom_e, const int* __restrict__ batch,
                       float* __restrict__ out){
  __shared__ float row[64];
  __shared__ float z[256];
  __shared__ float red[128];
  __shared__ float red2[128];
  const int b = blockIdx.x;       // n*64 + g
  const int n = b >> 6, g = b & 63;
  const int c = threadIdx.x;      // 0..127
  if(c < 64) row[c] = lg[b*64 + c];
  __syncthreads();
  float gf = bg[c];
  #pragma unroll 8
  for(int k=0;k<64;k++) gf = fmaf(row[k], Wg[k*128+c], gf);
  z[c] = pf[n*128+c]; z[128+c] = gf;
  __syncthreads();
  float tacc = b1[c];
  for(int qq=0;qq<256;qq++) tacc = fmaf(z[qq], W1[qq*128+c], tacc);
  tacc = lrelu(tacc);
  float s = 0.f;
  const float* ae = atom_e + n*1024;
  for(int i=c;i<1024;i+=128){ float v = ae[i]; s += (batch[i]==g) ? v : 0.f; }
  red[c] = tacc * W2[c];
  red2[c] = s;
  __syncthreads();
  for(int st=64; st>0; st>>=1){
    if(c<st){ red[c]+=red[c+st]; red2[c]+=red2[c+st]; }
    __syncthreads();
  }
  if(c==0) out[b] = red[0] + b2[0] + red2[0];
}

extern "C" void kernel_launch(void* const* d_in, const int* in_sizes, int n_in,
                              void* d_out, int out_size, void* d_ws, size_t ws_size,
                              hipStream_t stream) {
  const float* ms0   = (const float*)d_in[0];
  const float* ms1   = (const float*)d_in[1];
  const float* tfeat = (const float*)d_in[2];
  const float* la    = (const float*)d_in[3];
  const float* lg    = (const float*)d_in[4];
  const int*   batch = (const int*)  d_in[5];
  const float* Wtok  = (const float*)d_in[6];
  const float* btok  = (const float*)d_in[7];
  const float* Wc0   = (const float*)d_in[8];
  const float* bc0   = (const float*)d_in[9];
  const float* Wc1   = (const float*)d_in[10];
  const float* bc1   = (const float*)d_in[11];
  const float* Wp    = (const float*)d_in[12];
  const float* bp    = (const float*)d_in[13];
  const float* Wcat  = (const float*)d_in[14];
  const float* bcat  = (const float*)d_in[15];
  const float* Wgate = (const float*)d_in[16];
  const float* bgate = (const float*)d_in[17];
  const float* Wa    = (const float*)d_in[18];
  const float* ba    = (const float*)d_in[19];
  const float* Wgr   = (const float*)d_in[20];
  const float* bgr   = (const float*)d_in[21];
  const float* W1    = (const float*)d_in[22];
  const float* b1    = (const float*)d_in[23];
  const float* W2    = (const float*)d_in[24];
  const float* b2    = (const float*)d_in[25];
  const float* Wint  = (const float*)d_in[26];
  const float* bint  = (const float*)d_in[27];
  const float* Wpe   = (const float*)d_in[28];
  const float* bpe   = (const float*)d_in[29];
  const float* Wpg   = (const float*)d_in[30];
  const float* bpg   = (const float*)d_in[31];
  float* out = (float*)d_out;

  float* ws      = (float*)d_ws;
  float* tok     = ws;                         // 65536 f32
  float* S1      = ws + 65536;                 // 6912
  float* S0      = S1 + 6912;                  // 3456
  float* pp      = S0 + 3456;                  // 1024
  float* pf      = pp + 1024;                  // 512
  float* toksum  = pf + 512;                   // 512
  float* atom_e  = toksum + 512;               // 4096
  unsigned short* atoms_bf = (unsigned short*)(atom_e + 4096);   // 524288 u16
  unsigned short* Wt       = atoms_bf + 524288;                  // 16384 u16

  hipMemsetAsync(toksum, 0, 512*sizeof(float), stream);

  k_tok<<<NIMG*128, 256, 0, stream>>>(tfeat, Wtok, btok, tok, toksum);
  k_wsum<8,6><<<NIMG*64, 256, 0, stream>>>(ms1, S1);
  k_wsum<16,14><<<NIMG*32, 256, 0, stream>>>(ms0, S0);
  k_atoms<<<NIMG*1024, 128, 0, stream>>>(la, Wa, ba, atoms_bf, atom_e);
  k_wt<<<128, 128, 0, stream>>>(Wint, Wt);
  k_pconv<<<NIMG*128, 256, 0, stream>>>(S1, S0, Wc0, bc0, Wc1, bc1, pp);
  k_pf2<<<NIMG, 512, 0, stream>>>(pp, toksum, Wp, bp, Wcat, bcat, Wgate, bgate, pf);

  const int lds_bytes = 65536 + 4096;   // B dbuf + red
  hipFuncSetAttribute(reinterpret_cast<const void*>(k_inter),
                      hipFuncAttributeMaxDynamicSharedMemorySize, lds_bytes);
  k_inter<<<512, 512, lds_bytes, stream>>>(atoms_bf, tok, Wt, bint,
                                           Wpe, bpe, Wpg, bpg, atom_e);

  k_bias_seg<<<NIMG*64, 128, 0, stream>>>(lg, Wgr, bgr, pf, W1, b1, W2, b2,
                                          atom_e, batch, out);
}

// Round 7
// 215.511 us; speedup vs baseline: 2.9988x; 1.1607x over previous
//
#include <hip/hip_runtime.h>
#include <hip/hip_bf16.h>

#define NIMG 4

typedef __attribute__((ext_vector_type(8))) short short8v;
typedef __attribute__((ext_vector_type(4))) float float4v;
typedef __attribute__((ext_vector_type(4))) int   int4v;

__device__ __forceinline__ float sigm(float x){ return 1.f/(1.f+__expf(-x)); }
__device__ __forceinline__ float silu(float x){ return x/(1.f+__expf(-x)); }
__device__ __forceinline__ float lrelu(float x){ return fmaxf(x, 0.01f*x); }
__device__ __forceinline__ unsigned short f2bf(float f){
  union { float f; unsigned int i; } v; v.f = f;
  unsigned int r = v.i + 0x7fffu + ((v.i>>16)&1u);
  return (unsigned short)(r>>16); }

// DPP rotate-add within a 16-lane row (ctrl must be an immediate -> template)
template<int CTRL>
__device__ __forceinline__ float dpp_radd(float v){
  int s = __builtin_amdgcn_update_dpp(0, __builtin_bit_cast(int, v), CTRL, 0xF, 0xF, true);
  return v + __builtin_bit_cast(float, s);
}
__device__ __forceinline__ float row16_reduce(float v){
  v = dpp_radd<0x128>(v);  // row_ror:8
  v = dpp_radd<0x124>(v);  // row_ror:4
  v = dpp_radd<0x122>(v);  // row_ror:2
  v = dpp_radd<0x121>(v);  // row_ror:1
  return v;
}

// scale bf16x8 fragment by 8 f32 factors, repack to bf16x8
__device__ __forceinline__ short8v scale_frag(short8v a, const float* tv){
  int4v ai = __builtin_bit_cast(int4v, a);
  int4v oi;
  #pragma unroll
  for(int p=0;p<4;p++){
    float lo = __builtin_bit_cast(float, ai[p] << 16);
    float hi = __builtin_bit_cast(float, (int)(ai[p] & 0xFFFF0000));
    lo *= tv[2*p]; hi *= tv[2*p+1];
    int r;
    asm("v_cvt_pk_bf16_f32 %0, %1, %2" : "=v"(r) : "v"(lo), "v"(hi));
    oi[p] = r;
  }
  return __builtin_bit_cast(short8v, oi);
}

// ---------- windowed-sum device helper ----------
template<int DIM, int ODIM>
__device__ void wsum_body(const float* __restrict__ x, float* __restrict__ S,
                          int vb, float* sh){
  const float* xp = x + (size_t)vb*(DIM*DIM*DIM);
  for(int p=threadIdx.x; p<DIM*DIM*DIM; p+=256) sh[p] = silu(xp[p]);
  __syncthreads();
  const int wave = threadIdx.x>>6, lane = threadIdx.x&63;
  for(int tap=wave; tap<27; tap+=4){
    const int kd=tap/9, kh=(tap/3)%3, kw=tap%3;
    const int base = kd*DIM*DIM + kh*DIM + kw;
    float ps = 0.f;
    for(int idx=lane; idx<ODIM*ODIM*ODIM; idx+=64){
      int od = idx/(ODIM*ODIM); int r = idx - od*(ODIM*ODIM);
      int oh = r/ODIM; int ow = r - oh*ODIM;
      ps += sh[base + od*DIM*DIM + oh*DIM + ow];
    }
    #pragma unroll
    for(int m=32;m>=1;m>>=1) ps += __shfl_xor(ps,m);
    if(lane==0) S[vb*27 + tap] = ps;
  }
}

// ---------- K_pre: fused preprocessing (tok | wsum1 | wsum0 | atoms | wt) ----------
__global__ __launch_bounds__(256) void k_pre(
    const float* __restrict__ tf, const float* __restrict__ Wtok,
    const float* __restrict__ btok, float* __restrict__ tok,
    const float* __restrict__ ms1, float* __restrict__ S1,
    const float* __restrict__ ms0, float* __restrict__ S0,
    const float* __restrict__ la, const float* __restrict__ Wa,
    const float* __restrict__ ba, unsigned short* __restrict__ atoms_bf,
    float* __restrict__ atom_e,
    const float* __restrict__ Wint, unsigned short* __restrict__ Wt){
  __shared__ float sh[4096];
  const int b = blockIdx.x;
  const int tid = threadIdx.x;
  if(b < 512){
    // ---- tok ----
    const int row = b;
    sh[tid] = silu(tf[row*256 + tid]);
    __syncthreads();
    const int c = tid & 127, sg = tid >> 7;
    float acc = 0.f;
    #pragma unroll 8
    for(int q=sg*128; q<sg*128+128; q++) acc = fmaf(sh[q], Wtok[q*128+c], acc);
    if(sg==1) sh[256+c] = acc;
    __syncthreads();
    if(sg==0) tok[row*128+c] = acc + sh[256+c] + btok[c];
  } else if(b < 768){
    wsum_body<8,6>(ms1, S1, b-512, sh);
  } else if(b < 896){
    wsum_body<16,14>(ms0, S0, b-768, sh);
  } else if(b < 2944){
    // ---- atoms: 2 rows per block ----
    const int rowb = (b-896)*2;
    if(tid < 128) sh[tid] = la[(size_t)rowb*64 + tid];
    __syncthreads();
    const int r2 = tid>>7, c = tid&127;
    const float* s = sh + r2*64;
    float acc = ba[c];
    #pragma unroll 8
    for(int k=0;k<64;k++) acc = fmaf(s[k], Wa[k*128+c], acc);
    atoms_bf[(size_t)(rowb+r2)*128 + c] = f2bf(acc);
    if(tid<2) atom_e[rowb+tid] = 0.f;
  } else {
    // ---- Wt[c][k] = bf16(Wint[k][c]) ----
    const int idx = (b-2944)*256 + tid;
    const int c = idx >> 7, k = idx & 127;
    Wt[c*128 + k] = f2bf(Wint[k*128 + c]);
  }
}

// ---------- K_pconv: per-(n,c) conv dots + toksum ----------
__global__ void k_pconv(const float* __restrict__ S1, const float* __restrict__ S0,
                        const float* __restrict__ Wc0, const float* __restrict__ bc0,
                        const float* __restrict__ Wc1, const float* __restrict__ bc1,
                        const float* __restrict__ tok, float* __restrict__ toksum,
                        float* __restrict__ pp){
  const int b = blockIdx.x;        // n*128 + c
  const int n = b >> 7, c = b & 127;
  const int tid = threadIdx.x;     // 0..255
  float a0 = 0.f, a1 = 0.f, ts = 0.f;
  { const float* w = Wc0 + c*1728; const float* s = S1 + n*1728;
    for(int q=tid; q<1728; q+=256) a0 = fmaf(w[q], s[q], a0); }
  { const float* w = Wc1 + c*864;  const float* s = S0 + n*864;
    for(int q=tid; q<864; q+=256)  a1 = fmaf(w[q], s[q], a1); }
  for(int j=tid; j<128; j+=256) ts = tok[(n*128+j)*128 + c];
  #pragma unroll
  for(int m=32;m>=1;m>>=1){
    a0 += __shfl_xor(a0,m); a1 += __shfl_xor(a1,m); ts += __shfl_xor(ts,m);
  }
  __shared__ float r0[4], r1[4], r2[4];
  if((tid&63)==0){ r0[tid>>6]=a0; r1[tid>>6]=a1; r2[tid>>6]=ts; }
  __syncthreads();
  if(tid==0){
    float p0 = bc0[c] + (r0[0]+r0[1]+r0[2]+r0[3])*(1.f/216.f);
    float p1 = bc1[c] + (r1[0]+r1[1]+r1[2]+r1[3])*(1.f/2744.f);
    pp[n*256 + c]       = silu(p0);
    pp[n*256 + 128 + c] = silu(p1);
    toksum[n*128 + c]   = r2[0]+r2[1]+r2[2]+r2[3];
  }
}

// ---------- K_pf2: pocket + cat/gate -> pf[n,c] ----------
__global__ void k_pf2(const float* __restrict__ pp, const float* __restrict__ toksum,
                      const float* __restrict__ Wp,  const float* __restrict__ bp,
                      const float* __restrict__ Wcat, const float* __restrict__ bcat,
                      const float* __restrict__ Wgate,const float* __restrict__ bgate,
                      float* __restrict__ pf){
  __shared__ float ps[256];
  __shared__ float zz[384];
  __shared__ float part[4][128];
  __shared__ float partg[4][128];
  const int n = blockIdx.x;
  const int tid = threadIdx.x;     // 0..511
  const int c = tid & 127, s = tid >> 7;
  if(tid < 256) ps[tid] = pp[n*256 + tid];
  __syncthreads();
  float a = 0.f;
  for(int q=s*64; q<s*64+64; q++) a = fmaf(ps[q], Wp[q*128+c], a);
  part[s][c] = a;
  __syncthreads();
  if(s==0){
    float pk = bp[c] + part[0][c]+part[1][c]+part[2][c]+part[3][c];
    float ts = toksum[n*128+c];
    zz[c] = pk; zz[128+c] = ts; zz[256+c] = ts*(1.f/128.f);
  }
  __syncthreads();
  float a1=0.f, a2=0.f;
  for(int q=s*96; q<s*96+96; q++){
    float z = zz[q];
    a1 = fmaf(z, Wcat[q*128+c], a1);
    a2 = fmaf(z, Wgate[q*128+c], a2);
  }
  part[s][c]=a1; partg[s][c]=a2;
  __syncthreads();
  if(s==0){
    float v1 = bcat[c] +part[0][c]+part[1][c]+part[2][c]+part[3][c];
    float v2 = bgate[c]+partg[0][c]+partg[1][c]+partg[2][c]+partg[3][c];
    pf[n*128+c] = v1 * sigm(v2);
  }
}

// ---------- K_inter: fused interaction GEMM, register-resident B, DPP epilogue ----------
// 256 thr = 4 waves. Wave w: atom group g=w>>1 (32 atoms), c-half wc=w&1 (64 c).
// Block: 64 atoms x 8 j. Grid: 4 n x 16 chunks x 16 jg = 1024.
__global__ __launch_bounds__(256,2) void k_inter(
    const unsigned short* __restrict__ atoms_bf,  // [4096][128] bf16
    const float* __restrict__ tok,                // [512][128] f32
    const unsigned short* __restrict__ Wt,        // [128 c][128 k] bf16
    const float* __restrict__ bint,
    const float* __restrict__ Wpe, const float* __restrict__ bpe,
    const float* __restrict__ Wpg, const float* __restrict__ bpg,
    float* __restrict__ atom_e){
  __shared__ float red[2*2*2*32*2];               // [jb][g][wc][atom32][2]

  const int b0 = blockIdx.x;
  const int bid = (b0 & 7)*128 + (b0 >> 3);       // XCD swizzle (1024%8==0)
  const int n = bid >> 8;
  const int chunk = (bid >> 4) & 15;
  const int jg = bid & 15;                        // j base = jg*8
  const int tid = threadIdx.x;
  const int w = tid >> 6, lane = tid & 63;
  const int t = lane & 15, q = lane >> 4;
  const int g = w >> 1, wc = w & 1;

  const int rbase = n*1024 + chunk*64;

  // ---- A fragments (bf16, unscaled): row = rbase+g*32+fr*16+t, k = ks*32+q*8 ----
  short8v areg[2][4];
  { const unsigned short* ab = atoms_bf + (size_t)(rbase + g*32 + t)*128 + q*8;
    #pragma unroll
    for(int fr=0;fr<2;fr++)
      #pragma unroll
      for(int ks=0;ks<4;ks++)
        areg[fr][ks] = *(const short8v*)(ab + fr*16*128 + ks*32);
  }
  // ---- B fragments (W^T, j-invariant): c = wc*64+fc*16+t ----
  short8v breg[4][4];
  { const unsigned short* wb = Wt + (size_t)(wc*64 + t)*128 + q*8;
    #pragma unroll
    for(int fc=0;fc<4;fc++)
      #pragma unroll
      for(int ks=0;ks<4;ks++)
        breg[fc][ks] = *(const short8v*)(wb + fc*16*128 + ks*32);
  }
  // ---- epilogue constants ----
  float bi[4], wpe[4], wpg[4];
  #pragma unroll
  for(int fc=0;fc<4;fc++){
    int cc = wc*64 + fc*16 + t;
    bi[fc]=bint[cc]; wpe[fc]=Wpe[cc]; wpg[fc]=Wpg[cc];
  }
  const float bpe0 = bpe[0], bpg0 = bpg[0];
  const float* tokn = tok + (size_t)(n*128 + jg*8)*128 + q*8;

  float peacc = 0.f;

  for(int j=0;j<8;j++){
    const int jb = j & 1;
    // tok row slices for this lane's k positions
    float trv[4][8];
    { const float* tr = tokn + j*128;
      #pragma unroll
      for(int ks=0;ks<4;ks++){
        *(float4v*)&trv[ks][0] = *(const float4v*)(tr + ks*32);
        *(float4v*)&trv[ks][4] = *(const float4v*)(tr + ks*32 + 4);
      }
    }
    float4v acc[2][4];
    #pragma unroll
    for(int fr=0;fr<2;fr++)
      #pragma unroll
      for(int fc=0;fc<4;fc++)
        acc[fr][fc] = (float4v){bi[fc],bi[fc],bi[fc],bi[fc]};
    #pragma unroll
    for(int ks=0;ks<4;ks++){
      short8v s0 = scale_frag(areg[0][ks], trv[ks]);
      short8v s1 = scale_frag(areg[1][ks], trv[ks]);
      #pragma unroll
      for(int fc=0;fc<4;fc++){
        acc[0][fc] = __builtin_amdgcn_mfma_f32_16x16x32_bf16(s0, breg[fc][ks], acc[0][fc], 0,0,0);
        acc[1][fc] = __builtin_amdgcn_mfma_f32_16x16x32_bf16(s1, breg[fc][ks], acc[1][fc], 0,0,0);
      }
    }
    // epilogue: rows atom = g*32 + fr*16 + q*4 + r ; cols c in this wave's half
    #pragma unroll
    for(int fr=0;fr<2;fr++){
      #pragma unroll
      for(int r=0;r<4;r++){
        float d1=0.f, d2=0.f;
        #pragma unroll
        for(int fc=0;fc<4;fc++){
          float h = lrelu(acc[fr][fc][r]);
          d1 = fmaf(h, wpe[fc], d1);
          d2 = fmaf(h, wpg[fc], d2);
        }
        d1 = row16_reduce(d1);
        d2 = row16_reduce(d2);
        if(t==0){
          int a = fr*16 + q*4 + r;
          float* rp = red + (((jb*2+g)*2+wc)*32 + a)*2;
          rp[0] = d1; rp[1] = d2;
        }
      }
    }
    __syncthreads();
    if(wc==0 && lane<32){
      const float* rp = red + (((jb*2+g)*2+0)*32 + lane)*2;
      const float* rq = red + (((jb*2+g)*2+1)*32 + lane)*2;
      float d1 = rp[0]+rq[0], d2 = rp[1]+rq[1];
      peacc += (d1 + bpe0) * sigm(d2 + bpg0);
    }
  }
  if(wc==0 && lane<32) atomicAdd(atom_e + rbase + g*32 + lane, peacc);
}

// ---------- K_bias_seg: bias head + fused segment-sum ----------
__global__ void k_bias_seg(const float* __restrict__ lg, const float* __restrict__ Wg,
                       const float* __restrict__ bg, const float* __restrict__ pf,
                       const float* __restrict__ W1, const float* __restrict__ b1,
                       const float* __restrict__ W2, const float* __restrict__ b2,
                       const float* __restrict__ atom_e, const int* __restrict__ batch,
                       float* __restrict__ out){
  __shared__ float row[64];
  __shared__ float z[256];
  __shared__ float red[128];
  __shared__ float red2[128];
  const int b = blockIdx.x;       // n*64 + g
  const int n = b >> 6, g = b & 63;
  const int c = threadIdx.x;      // 0..127
  if(c < 64) row[c] = lg[b*64 + c];
  __syncthreads();
  float gf = bg[c];
  #pragma unroll 8
  for(int k=0;k<64;k++) gf = fmaf(row[k], Wg[k*128+c], gf);
  z[c] = pf[n*128+c]; z[128+c] = gf;
  __syncthreads();
  float tacc = b1[c];
  for(int qq=0;qq<256;qq++) tacc = fmaf(z[qq], W1[qq*128+c], tacc);
  tacc = lrelu(tacc);
  float s = 0.f;
  const float* ae = atom_e + n*1024;
  for(int i=c;i<1024;i+=128){ float v = ae[i]; s += (batch[i]==g) ? v : 0.f; }
  red[c] = tacc * W2[c];
  red2[c] = s;
  __syncthreads();
  for(int st=64; st>0; st>>=1){
    if(c<st){ red[c]+=red[c+st]; red2[c]+=red2[c+st]; }
    __syncthreads();
  }
  if(c==0) out[b] = red[0] + b2[0] + red2[0];
}

extern "C" void kernel_launch(void* const* d_in, const int* in_sizes, int n_in,
                              void* d_out, int out_size, void* d_ws, size_t ws_size,
                              hipStream_t stream) {
  const float* ms0   = (const float*)d_in[0];
  const float* ms1   = (const float*)d_in[1];
  const float* tfeat = (const float*)d_in[2];
  const float* la    = (const float*)d_in[3];
  const float* lg    = (const float*)d_in[4];
  const int*   batch = (const int*)  d_in[5];
  const float* Wtok  = (const float*)d_in[6];
  const float* btok  = (const float*)d_in[7];
  const float* Wc0   = (const float*)d_in[8];
  const float* bc0   = (const float*)d_in[9];
  const float* Wc1   = (const float*)d_in[10];
  const float* bc1   = (const float*)d_in[11];
  const float* Wp    = (const float*)d_in[12];
  const float* bp    = (const float*)d_in[13];
  const float* Wcat  = (const float*)d_in[14];
  const float* bcat  = (const float*)d_in[15];
  const float* Wgate = (const float*)d_in[16];
  const float* bgate = (const float*)d_in[17];
  const float* Wa    = (const float*)d_in[18];
  const float* ba    = (const float*)d_in[19];
  const float* Wgr   = (const float*)d_in[20];
  const float* bgr   = (const float*)d_in[21];
  const float* W1    = (const float*)d_in[22];
  const float* b1    = (const float*)d_in[23];
  const float* W2    = (const float*)d_in[24];
  const float* b2    = (const float*)d_in[25];
  const float* Wint  = (const float*)d_in[26];
  const float* bint  = (const float*)d_in[27];
  const float* Wpe   = (const float*)d_in[28];
  const float* bpe   = (const float*)d_in[29];
  const float* Wpg   = (const float*)d_in[30];
  const float* bpg   = (const float*)d_in[31];
  float* out = (float*)d_out;

  float* ws      = (float*)d_ws;
  float* tok     = ws;                         // 65536 f32
  float* S1      = ws + 65536;                 // 6912
  float* S0      = S1 + 6912;                  // 3456
  float* pp      = S0 + 3456;                  // 1024
  float* pf      = pp + 1024;                  // 512
  float* toksum  = pf + 512;                   // 512
  float* atom_e  = toksum + 512;               // 4096
  unsigned short* atoms_bf = (unsigned short*)(atom_e + 4096);   // 524288 u16
  unsigned short* Wt       = atoms_bf + 524288;                  // 16384 u16

  k_pre<<<3008, 256, 0, stream>>>(tfeat, Wtok, btok, tok,
                                  ms1, S1, ms0, S0,
                                  la, Wa, ba, atoms_bf, atom_e,
                                  Wint, Wt);
  k_inter<<<1024, 256, 0, stream>>>(atoms_bf, tok, Wt, bint,
                                    Wpe, bpe, Wpg, bpg, atom_e);
  k_pconv<<<NIMG*128, 256, 0, stream>>>(S1, S0, Wc0, bc0, Wc1, bc1,
                                        tok, toksum, pp);
  k_pf2<<<NIMG, 512, 0, stream>>>(pp, toksum, Wp, bp, Wcat, bcat, Wgate, bgate, pf);
  k_bias_seg<<<NIMG*64, 128, 0, stream>>>(lg, Wgr, bgr, pf, W1, b1, W2, b2,
                                          atom_e, batch, out);
}